// Round 9
// baseline (50.991 us; speedup 1.0000x reference)
//
#include <hip/hip_runtime.h>

#define BB 4
#define TT 4096
#define CUT 2048
#define CE 1024
#define HD 64
#define QSC 0.045084220027780106f   // 1024^-0.5 * log2(e)

typedef unsigned short u16;
typedef unsigned int u32;
typedef __attribute__((ext_vector_type(8))) short bf16x8;
typedef __attribute__((ext_vector_type(4))) float f32x4;

__device__ __forceinline__ u16 f2b(float f) {
  union { float f; unsigned u; } v; v.f = f;
  unsigned r = v.u + 0x7fffu + ((v.u >> 16) & 1u);   // RNE to bf16
  return (u16)(r >> 16);
}

__device__ __forceinline__ u32 cvtpk(float lo, float hi) {
  u32 r;
  asm("v_cvt_pk_bf16_f32 %0, %1, %2" : "=v"(r) : "v"(lo), "v"(hi));
  return r;
}

// async global->LDS: per-lane 16B from g+lane*16, written to ldsbase+lane*16
__device__ __forceinline__ void gld16(const u16* g, u16* l) {
  __builtin_amdgcn_global_load_lds((const __attribute__((address_space(1))) u32*)g,
                                   (__attribute__((address_space(3))) u32*)l, 16, 0, 0);
}

// ---- Kernel 1: W3F = W in MFMA B-fragment order (UNCHANGED) ----
__global__ void wtrans_k(const float* __restrict__ Wk, const float* __restrict__ Wv,
                         const float* __restrict__ Wq, u16* __restrict__ w3f) {
  int id = blockIdx.x * 256 + threadIdx.x;     // 196608 total
  int j    = id & 7;
  int lane = (id >> 3) & 63;
  int f    = id >> 9;                          // 0..383
  int kstep = f & 31;
  int mnt   = f >> 5;
  int m  = mnt >> 2;
  int nt = mnt & 3;
  int k   = kstep * 32 + (lane >> 4) * 8 + j;
  int col = nt * 16 + (lane & 15);
  const float* W = (m == 0) ? Wk : (m == 1) ? Wv : Wq;
  w3f[id] = f2b(W[k * 64 + col]);
}

// ---- Kernel 2: QKV projection (UNCHANGED from round 8) ----
__launch_bounds__(256, 2)
__global__ void proj_k(const float* __restrict__ x, const u16* __restrict__ w3f,
                       const float* __restrict__ bk, const float* __restrict__ bv,
                       const float* __restrict__ bq,
                       u16* __restrict__ KF, u16* __restrict__ VF, u16* __restrict__ Qb) {
  __shared__ u16  st[2][2][12][512];            // [buf][half][mnt][frag] 48KB
  __shared__ f32x4 cl[2][12][64];               // K-combine 24KB
  const int tid  = threadIdx.x;
  const int lane = tid & 63;
  const int wv   = tid >> 6;                    // 0..3
  const int rg   = wv & 1;                      // row-group (16 rows)
  const int kh   = wv >> 1;                     // K-half
  const int l15  = lane & 15;
  const int g    = lane >> 4;
  const int r0   = blockIdx.x * 32;

  f32x4 acc[12];
  #pragma unroll
  for (int t = 0; t < 12; ++t) acc[t] = (f32x4){0.f, 0.f, 0.f, 0.f};

  const float* xrow = x + (size_t)(r0 + rg * 16 + l15) * CE + kh * 512;

  #define STAGE(buf, t)                                                        \
    {                                                                          \
      _Pragma("unroll")                                                        \
      for (int i = 0; i < 6; ++i) {                                            \
        int jj = wv * 6 + i;                                                   \
        int hh = jj / 12, mm = jj % 12;                                        \
        gld16(&w3f[(size_t)(mm * 32 + hh * 16 + (t)) * 512 + lane * 8],        \
              &st[buf][hh][mm][0]);                                            \
      }                                                                        \
    }

  f32x4 xs[2][2];
  xs[0][0] = *(const f32x4*)(xrow + g * 8);
  xs[0][1] = *(const f32x4*)(xrow + g * 8 + 4);
  STAGE(0, 0);
  asm volatile("s_waitcnt vmcnt(0)" ::: "memory");
  __syncthreads();

  #pragma unroll
  for (int t = 0; t < 16; ++t) {
    const int cur = t & 1, nxt = cur ^ 1;
    if (t < 15) {
      STAGE(nxt, t + 1);
      const float* xp = xrow + (t + 1) * 32 + g * 8;
      xs[nxt][0] = *(const f32x4*)xp;
      xs[nxt][1] = *(const f32x4*)(xp + 4);
    }
    bf16x8 a;
    #pragma unroll
    for (int j = 0; j < 4; ++j) {
      a[j]     = (short)f2b(xs[cur][0][j]);
      a[j + 4] = (short)f2b(xs[cur][1][j]);
    }
    #pragma unroll
    for (int mnt = 0; mnt < 12; ++mnt) {
      bf16x8 bfr = *(const bf16x8*)&st[cur][kh][mnt][lane * 8];
      acc[mnt] = __builtin_amdgcn_mfma_f32_16x16x32_bf16(a, bfr, acc[mnt], 0, 0, 0);
    }
    asm volatile("s_waitcnt vmcnt(0)" ::: "memory");
    __syncthreads();
  }
  #undef STAGE

  if (kh == 1) {
    #pragma unroll
    for (int t = 0; t < 12; ++t) cl[rg][t][lane] = acc[t];
  }
  __syncthreads();
  if (kh == 0) {
    #pragma unroll
    for (int t = 0; t < 12; ++t) acc[t] += cl[rg][t][lane];

    const int b    = r0 >> 12;
    const int cch  = (r0 >> 6) & 63;
    const int half = (r0 >> 5) & 1;
    const int h    = rg;

    const int t0 = r0 & (TT - 1);
    if (t0 >= CUT) {
      const int trow = t0 - CUT + h * 16;
      #pragma unroll
      for (int nt = 0; nt < 4; ++nt) {
        int col = nt * 16 + l15;
        float bc = bq[col];
        #pragma unroll
        for (int r = 0; r < 4; ++r)
          Qb[((size_t)b * CUT + trow + g * 4 + r) * HD + col] =
              f2b((acc[8 + nt][r] + bc) * QSC);
      }
    }
    {
      u16* KFc = KF + ((size_t)(b * 64 + cch) * 8) * 512;
      const int kt2 = (half * 2 + h) * 2;
      #pragma unroll
      for (int nt = 0; nt < 4; ++nt) {
        int col = nt * 16 + l15;
        float bc = bk[col];
        f32x4 v = acc[nt];
        const int off = (kt2 + (nt >> 1)) * 512 + 128 * ((nt & 1) * 2 + (l15 >> 3)) + (l15 & 7);
        #pragma unroll
        for (int r = 0; r < 4; ++r)
          KFc[off + (g * 4 + r) * 8] = f2b(v[r] + bc);
      }
    }
    {
      u16* VFc = VF + ((size_t)(b * 64 + cch) * 8) * 512;
      #pragma unroll
      for (int nt = 0; nt < 4; ++nt) {
        int col = nt * 16 + l15;
        float bc = bv[col];
        f32x4 v = acc[4 + nt];
        #pragma unroll
        for (int r = 0; r < 4; ++r) {
          int tt = h * 16 + g * 4 + r;
          VFc[(half * 4 + nt) * 512 + (l15 + 16 * (tt >> 3)) * 8 + (tt & 7)] = f2b(v[r] + bc);
        }
      }
    }
  }
}

// ---- Kernel 3: attention. QBLK=32 (halved L2 traffic), K prefetch ping-pong,
// both q-halves share ka/va registers; per-half softmax+PV through PLd.
__launch_bounds__(512, 2)
__global__ void attn_k(const u16* __restrict__ Qb, const u16* __restrict__ KF,
                       const u16* __restrict__ VF, float* __restrict__ out) {
  __shared__ u32   PLd[8][16][36];              // per-wave P (bf16 pairs)
  __shared__ float OO[8][16][66];               // per-wave unnormalized O (one half)
  __shared__ float OL[8][32];                   // per-wave l-sum per q (both halves)
  const int tid  = threadIdx.x;
  const int lane = tid & 63;
  const int wv   = tid >> 6;
  const int l15  = lane & 15;
  const int g    = lane >> 4;
  const int id   = blockIdx.x;                  // 0..255
  const int b    = id & 3;
  const int i0   = (id >> 2) * 32;

  const int qmin = CUT + i0;

  bf16x8 qf[2][2];
  #pragma unroll
  for (int h = 0; h < 2; ++h) {
    const u16* qrow = Qb + ((size_t)b * CUT + i0 + h * 16 + l15) * HD;
    qf[h][0] = *(const bf16x8*)&qrow[g * 8];
    qf[h][1] = *(const bf16x8*)&qrow[32 + g * 8];
  }

  f32x4 o[2][4];
  #pragma unroll
  for (int h = 0; h < 2; ++h)
    #pragma unroll
    for (int dt = 0; dt < 4; ++dt) o[h][dt] = (f32x4){0.f, 0.f, 0.f, 0.f};
  float lsum[2] = {0.f, 0.f};

  const int nch = (CUT + i0 + 32 + 63) >> 6;    // 33..64 chunks
  const u16* KFb = KF + (size_t)b * 64 * 8 * 512;
  const u16* VFb = VF + (size_t)b * 64 * 8 * 512;

  // preload K for first chunk
  bf16x8 ka[4][2];
  {
    const u16* kp = KFb + (size_t)wv * 4096 + lane * 8;
    #pragma unroll
    for (int kt = 0; kt < 4; ++kt) {
      ka[kt][0] = *(const bf16x8*)(kp + (kt * 2 + 0) * 512);
      ka[kt][1] = *(const bf16x8*)(kp + (kt * 2 + 1) * 512);
    }
  }

  for (int c = wv; c < nch; c += 8) {
    const int kv0 = c << 6;

    // V loads for current chunk (consumed after both QK halves + softmax)
    const u16* vp = VFb + (size_t)c * 4096 + lane * 8;
    bf16x8 va[2][4];
    #pragma unroll
    for (int c2 = 0; c2 < 2; ++c2)
      #pragma unroll
      for (int dt = 0; dt < 4; ++dt)
        va[c2][dt] = *(const bf16x8*)(vp + (c2 * 4 + dt) * 512);

    // prefetch next chunk's K
    bf16x8 kb[4][2];
    const int cn = c + 8;
    if (cn < nch) {
      const u16* kp = KFb + (size_t)cn * 4096 + lane * 8;
      #pragma unroll
      for (int kt = 0; kt < 4; ++kt) {
        kb[kt][0] = *(const bf16x8*)(kp + (kt * 2 + 0) * 512);
        kb[kt][1] = *(const bf16x8*)(kp + (kt * 2 + 1) * 512);
      }
    }

    // QK^T for both halves (shared ka)
    f32x4 st[2][4];
    __builtin_amdgcn_s_setprio(1);
    #pragma unroll
    for (int h = 0; h < 2; ++h)
      #pragma unroll
      for (int kt = 0; kt < 4; ++kt) {
        f32x4 s = (f32x4){0.f, 0.f, 0.f, 0.f};
        s = __builtin_amdgcn_mfma_f32_16x16x32_bf16(ka[kt][0], qf[h][0], s, 0, 0, 0);
        s = __builtin_amdgcn_mfma_f32_16x16x32_bf16(ka[kt][1], qf[h][1], s, 0, 0, 0);
        st[h][kt] = s;
      }
    __builtin_amdgcn_s_setprio(0);

    // softmax (fixed max; scale*log2e folded into Q)
    #pragma unroll
    for (int h = 0; h < 2; ++h) {
      if (kv0 + 63 <= qmin + h * 16) {          // wave-uniform fully-unmasked chunk
        #pragma unroll
        for (int kt = 0; kt < 4; ++kt)
          #pragma unroll
          for (int r = 0; r < 4; ++r) {
            float p = exp2f(st[h][kt][r]);
            st[h][kt][r] = p;
            lsum[h] += p;
          }
      } else {
        const int qabs = qmin + h * 16 + l15;
        #pragma unroll
        for (int kt = 0; kt < 4; ++kt)
          #pragma unroll
          for (int r = 0; r < 4; ++r) {
            int key = kv0 + kt * 16 + g * 4 + r;
            float p = exp2f(st[h][kt][r]);
            p = (key <= qabs) ? p : 0.f;
            st[h][kt][r] = p;
            lsum[h] += p;
          }
      }
    }

    // per half: pack P -> LDS, then PV (wave-private LDS reuse is in-order)
    #pragma unroll
    for (int h = 0; h < 2; ++h) {
      #pragma unroll
      for (int kt = 0; kt < 4; ++kt) {
        u32 d0 = cvtpk(st[h][kt][0], st[h][kt][1]);
        u32 d1 = cvtpk(st[h][kt][2], st[h][kt][3]);
        u32* p = &PLd[wv][l15][kt * 8 + g * 2];
        p[0] = d0; p[1] = d1;
      }
      __builtin_amdgcn_s_setprio(1);
      #pragma unroll
      for (int c2 = 0; c2 < 2; ++c2) {
        bf16x8 pa = *(const bf16x8*)&PLd[wv][l15][c2 * 16 + g * 4];
        #pragma unroll
        for (int dt = 0; dt < 4; ++dt)
          o[h][dt] = __builtin_amdgcn_mfma_f32_16x16x32_bf16(pa, va[c2][dt], o[h][dt], 0, 0, 0);
      }
      __builtin_amdgcn_s_setprio(0);
    }

    // rotate prefetched K
    if (cn < nch) {
      #pragma unroll
      for (int kt = 0; kt < 4; ++kt) {
        ka[kt][0] = kb[kt][0];
        ka[kt][1] = kb[kt][1];
      }
    }
  }

  // ---- l reduce over g-groups; publish both halves ----
  #pragma unroll
  for (int h = 0; h < 2; ++h) {
    float ls = lsum[h];
    ls += __shfl_xor(ls, 16);
    ls += __shfl_xor(ls, 32);
    if (lane < 16) OL[wv][h * 16 + l15] = ls;
  }

  // ---- combine in two 16-row phases (OO reused) ----
  #pragma unroll
  for (int ph = 0; ph < 2; ++ph) {
    #pragma unroll
    for (int dt = 0; dt < 4; ++dt)
      #pragma unroll
      for (int r = 0; r < 4; ++r)
        OO[wv][g * 4 + r][dt * 16 + l15] = o[ph][dt][r];
    __syncthreads();
    #pragma unroll
    for (int e = tid; e < 1024; e += 512) {
      int q = e >> 6, d = e & 63;
      float L = 0.f, O = 0.f;
      #pragma unroll
      for (int w = 0; w < 8; ++w) { L += OL[w][ph * 16 + q]; O += OO[w][q][d]; }
      out[((size_t)b * CUT + i0 + ph * 16 + q) * HD + d] = O / L;
    }
    __syncthreads();
  }
}

extern "C" void kernel_launch(void* const* d_in, const int* in_sizes, int n_in,
                              void* d_out, int out_size, void* d_ws, size_t ws_size,
                              hipStream_t stream) {
  const float* x  = (const float*)d_in[0];
  const float* Wq = (const float*)d_in[1];
  const float* bq = (const float*)d_in[2];
  const float* Wk = (const float*)d_in[3];
  const float* bk = (const float*)d_in[4];
  const float* Wv = (const float*)d_in[5];
  const float* bv = (const float*)d_in[6];
  float* out = (float*)d_out;

  u16* Qb  = (u16*)d_ws;                               // [B*CUT*64] (pre-scaled)
  u16* W3F = Qb + (size_t)BB * CUT * HD;               // [384*512]  frag-ordered W
  u16* KF  = W3F + (size_t)384 * 512;                  // [B*64*8*512] frag-ordered K
  u16* VF  = KF + (size_t)BB * 64 * 8 * 512;           // [B*64*8*512] frag-ordered V

  wtrans_k<<<768, 256, 0, stream>>>(Wk, Wv, Wq, W3F);
  proj_k<<<512, 256, 0, stream>>>(x, W3F, bk, bv, bq, KF, VF, Qb);
  attn_k<<<256, 512, 0, stream>>>(Qb, KF, VF, out);
}

// Round 10
// 47.695 us; speedup vs baseline: 1.0691x; 1.0691x over previous
//
#include <hip/hip_runtime.h>

#define BB 4
#define TT 4096
#define CUT 2048
#define CE 1024
#define HD 64
#define QSC 0.045084220027780106f   // 1024^-0.5 * log2(e)

typedef unsigned short u16;
typedef unsigned int u32;
typedef __attribute__((ext_vector_type(8))) short bf16x8;
typedef __attribute__((ext_vector_type(4))) float f32x4;

__device__ __forceinline__ u16 f2b(float f) {
  union { float f; unsigned u; } v; v.f = f;
  unsigned r = v.u + 0x7fffu + ((v.u >> 16) & 1u);   // RNE to bf16
  return (u16)(r >> 16);
}

__device__ __forceinline__ u32 cvtpk(float lo, float hi) {
  u32 r;
  asm("v_cvt_pk_bf16_f32 %0, %1, %2" : "=v"(r) : "v"(lo), "v"(hi));
  return r;
}

// async global->LDS: per-lane 16B from g+lane*16, written to ldsbase+lane*16
__device__ __forceinline__ void gld16(const u16* g, u16* l) {
  __builtin_amdgcn_global_load_lds((const __attribute__((address_space(1))) u32*)g,
                                   (__attribute__((address_space(3))) u32*)l, 16, 0, 0);
}

// ---- Kernel 1: W3F = W in MFMA B-fragment order (UNCHANGED) ----
__global__ void wtrans_k(const float* __restrict__ Wk, const float* __restrict__ Wv,
                         const float* __restrict__ Wq, u16* __restrict__ w3f) {
  int id = blockIdx.x * 256 + threadIdx.x;     // 196608 total
  int j    = id & 7;
  int lane = (id >> 3) & 63;
  int f    = id >> 9;                          // 0..383
  int kstep = f & 31;
  int mnt   = f >> 5;
  int m  = mnt >> 2;
  int nt = mnt & 3;
  int k   = kstep * 32 + (lane >> 4) * 8 + j;
  int col = nt * 16 + (lane & 15);
  const float* W = (m == 0) ? Wk : (m == 1) ? Wv : Wq;
  w3f[id] = f2b(W[k * 64 + col]);
}

// ---- Kernel 2: QKV projection. Counted-vmcnt pipeline: raw s_barrier with
// s_waitcnt vmcnt(2) (staging retired, x HBM prefetch stays in flight across
// the barrier). __syncthreads would drain vmcnt to 0 every iteration.
__launch_bounds__(256, 2)
__global__ void proj_k(const float* __restrict__ x, const u16* __restrict__ w3f,
                       const float* __restrict__ bk, const float* __restrict__ bv,
                       const float* __restrict__ bq,
                       u16* __restrict__ KF, u16* __restrict__ VF, u16* __restrict__ Qb) {
  __shared__ u16  st[2][2][12][512];            // [buf][half][mnt][frag] 48KB
  __shared__ f32x4 cl[2][12][64];               // K-combine 24KB
  const int tid  = threadIdx.x;
  const int lane = tid & 63;
  const int wv   = tid >> 6;                    // 0..3
  const int rg   = wv & 1;                      // row-group (16 rows)
  const int kh   = wv >> 1;                     // K-half
  const int l15  = lane & 15;
  const int g    = lane >> 4;
  const int r0   = blockIdx.x * 32;

  f32x4 acc[12];
  #pragma unroll
  for (int t = 0; t < 12; ++t) acc[t] = (f32x4){0.f, 0.f, 0.f, 0.f};

  const float* xrow = x + (size_t)(r0 + rg * 16 + l15) * CE + kh * 512;

  // staging: wave stages frags j = wv*6 .. wv*6+5;  h=j/12, mnt=j%12
  #define STAGE(buf, t)                                                        \
    {                                                                          \
      _Pragma("unroll")                                                        \
      for (int i = 0; i < 6; ++i) {                                            \
        int jj = wv * 6 + i;                                                   \
        int hh = jj / 12, mm = jj % 12;                                        \
        gld16(&w3f[(size_t)(mm * 32 + hh * 16 + (t)) * 512 + lane * 8],        \
              &st[buf][hh][mm][0]);                                            \
      }                                                                        \
    }

  f32x4 xs[2][2];
  STAGE(0, 0);
  __builtin_amdgcn_sched_barrier(0);
  xs[0][0] = *(const f32x4*)(xrow + g * 8);
  xs[0][1] = *(const f32x4*)(xrow + g * 8 + 4);
  asm volatile("s_waitcnt vmcnt(0)" ::: "memory");
  __builtin_amdgcn_s_barrier();

  #pragma unroll
  for (int t = 0; t < 16; ++t) {
    const int cur = t & 1, nxt = cur ^ 1;
    if (t < 15) {
      STAGE(nxt, t + 1);                        // 6 gld_lds (oldest in this batch)
      __builtin_amdgcn_sched_barrier(0);        // pin issue order: stage before x
      const float* xp = xrow + (t + 1) * 32 + g * 8;
      xs[nxt][0] = *(const f32x4*)xp;
      xs[nxt][1] = *(const f32x4*)(xp + 4);
      __builtin_amdgcn_sched_barrier(0);
    }
    bf16x8 a;
    #pragma unroll
    for (int j = 0; j < 4; ++j) {
      a[j]     = (short)f2b(xs[cur][0][j]);
      a[j + 4] = (short)f2b(xs[cur][1][j]);
    }
    #pragma unroll
    for (int mnt = 0; mnt < 12; ++mnt) {
      bf16x8 bfr = *(const bf16x8*)&st[cur][kh][mnt][lane * 8];
      acc[mnt] = __builtin_amdgcn_mfma_f32_16x16x32_bf16(a, bfr, acc[mnt], 0, 0, 0);
    }
    if (t < 15) {
      // 6 oldest (staging) retired; 2 newest (x HBM prefetch) may stay in flight
      asm volatile("s_waitcnt vmcnt(2)" ::: "memory");
    } else {
      asm volatile("s_waitcnt vmcnt(0)" ::: "memory");
    }
    __builtin_amdgcn_s_barrier();
  }
  #undef STAGE

  // ---- K-half combine (cold path; full barriers fine) ----
  if (kh == 1) {
    #pragma unroll
    for (int t = 0; t < 12; ++t) cl[rg][t][lane] = acc[t];
  }
  __syncthreads();
  if (kh == 0) {
    #pragma unroll
    for (int t = 0; t < 12; ++t) acc[t] += cl[rg][t][lane];

    const int b    = r0 >> 12;
    const int cch  = (r0 >> 6) & 63;
    const int half = (r0 >> 5) & 1;
    const int h    = rg;

    const int t0 = r0 & (TT - 1);
    if (t0 >= CUT) {
      const int trow = t0 - CUT + h * 16;
      #pragma unroll
      for (int nt = 0; nt < 4; ++nt) {
        int col = nt * 16 + l15;
        float bc = bq[col];
        #pragma unroll
        for (int r = 0; r < 4; ++r)
          Qb[((size_t)b * CUT + trow + g * 4 + r) * HD + col] =
              f2b((acc[8 + nt][r] + bc) * QSC);
      }
    }
    {
      u16* KFc = KF + ((size_t)(b * 64 + cch) * 8) * 512;
      const int kt2 = (half * 2 + h) * 2;
      #pragma unroll
      for (int nt = 0; nt < 4; ++nt) {
        int col = nt * 16 + l15;
        float bc = bk[col];
        f32x4 v = acc[nt];
        const int off = (kt2 + (nt >> 1)) * 512 + 128 * ((nt & 1) * 2 + (l15 >> 3)) + (l15 & 7);
        #pragma unroll
        for (int r = 0; r < 4; ++r)
          KFc[off + (g * 4 + r) * 8] = f2b(v[r] + bc);
      }
    }
    {
      u16* VFc = VF + ((size_t)(b * 64 + cch) * 8) * 512;
      #pragma unroll
      for (int nt = 0; nt < 4; ++nt) {
        int col = nt * 16 + l15;
        float bc = bv[col];
        f32x4 v = acc[4 + nt];
        #pragma unroll
        for (int r = 0; r < 4; ++r) {
          int tt = h * 16 + g * 4 + r;
          VFc[(half * 4 + nt) * 512 + (l15 + 16 * (tt >> 3)) * 8 + (tt & 7)] = f2b(v[r] + bc);
        }
      }
    }
  }
}

// ---- Kernel 3: attention (UNCHANGED from round 9 for clean attribution) ----
__launch_bounds__(512, 2)
__global__ void attn_k(const u16* __restrict__ Qb, const u16* __restrict__ KF,
                       const u16* __restrict__ VF, float* __restrict__ out) {
  __shared__ u32   PLd[8][16][36];              // per-wave P (bf16 pairs)
  __shared__ float OO[8][16][66];               // per-wave unnormalized O (one half)
  __shared__ float OL[8][32];                   // per-wave l-sum per q (both halves)
  const int tid  = threadIdx.x;
  const int lane = tid & 63;
  const int wv   = tid >> 6;
  const int l15  = lane & 15;
  const int g    = lane >> 4;
  const int id   = blockIdx.x;                  // 0..255
  const int b    = id & 3;
  const int i0   = (id >> 2) * 32;

  const int qmin = CUT + i0;

  bf16x8 qf[2][2];
  #pragma unroll
  for (int h = 0; h < 2; ++h) {
    const u16* qrow = Qb + ((size_t)b * CUT + i0 + h * 16 + l15) * HD;
    qf[h][0] = *(const bf16x8*)&qrow[g * 8];
    qf[h][1] = *(const bf16x8*)&qrow[32 + g * 8];
  }

  f32x4 o[2][4];
  #pragma unroll
  for (int h = 0; h < 2; ++h)
    #pragma unroll
    for (int dt = 0; dt < 4; ++dt) o[h][dt] = (f32x4){0.f, 0.f, 0.f, 0.f};
  float lsum[2] = {0.f, 0.f};

  const int nch = (CUT + i0 + 32 + 63) >> 6;    // 33..64 chunks
  const u16* KFb = KF + (size_t)b * 64 * 8 * 512;
  const u16* VFb = VF + (size_t)b * 64 * 8 * 512;

  bf16x8 ka[4][2];
  {
    const u16* kp = KFb + (size_t)wv * 4096 + lane * 8;
    #pragma unroll
    for (int kt = 0; kt < 4; ++kt) {
      ka[kt][0] = *(const bf16x8*)(kp + (kt * 2 + 0) * 512);
      ka[kt][1] = *(const bf16x8*)(kp + (kt * 2 + 1) * 512);
    }
  }

  for (int c = wv; c < nch; c += 8) {
    const int kv0 = c << 6;

    const u16* vp = VFb + (size_t)c * 4096 + lane * 8;
    bf16x8 va[2][4];
    #pragma unroll
    for (int c2 = 0; c2 < 2; ++c2)
      #pragma unroll
      for (int dt = 0; dt < 4; ++dt)
        va[c2][dt] = *(const bf16x8*)(vp + (c2 * 4 + dt) * 512);

    bf16x8 kb[4][2];
    const int cn = c + 8;
    if (cn < nch) {
      const u16* kp = KFb + (size_t)cn * 4096 + lane * 8;
      #pragma unroll
      for (int kt = 0; kt < 4; ++kt) {
        kb[kt][0] = *(const bf16x8*)(kp + (kt * 2 + 0) * 512);
        kb[kt][1] = *(const bf16x8*)(kp + (kt * 2 + 1) * 512);
      }
    }

    f32x4 st[2][4];
    __builtin_amdgcn_s_setprio(1);
    #pragma unroll
    for (int h = 0; h < 2; ++h)
      #pragma unroll
      for (int kt = 0; kt < 4; ++kt) {
        f32x4 s = (f32x4){0.f, 0.f, 0.f, 0.f};
        s = __builtin_amdgcn_mfma_f32_16x16x32_bf16(ka[kt][0], qf[h][0], s, 0, 0, 0);
        s = __builtin_amdgcn_mfma_f32_16x16x32_bf16(ka[kt][1], qf[h][1], s, 0, 0, 0);
        st[h][kt] = s;
      }
    __builtin_amdgcn_s_setprio(0);

    #pragma unroll
    for (int h = 0; h < 2; ++h) {
      if (kv0 + 63 <= qmin + h * 16) {
        #pragma unroll
        for (int kt = 0; kt < 4; ++kt)
          #pragma unroll
          for (int r = 0; r < 4; ++r) {
            float p = exp2f(st[h][kt][r]);
            st[h][kt][r] = p;
            lsum[h] += p;
          }
      } else {
        const int qabs = qmin + h * 16 + l15;
        #pragma unroll
        for (int kt = 0; kt < 4; ++kt)
          #pragma unroll
          for (int r = 0; r < 4; ++r) {
            int key = kv0 + kt * 16 + g * 4 + r;
            float p = exp2f(st[h][kt][r]);
            p = (key <= qabs) ? p : 0.f;
            st[h][kt][r] = p;
            lsum[h] += p;
          }
      }
    }

    #pragma unroll
    for (int h = 0; h < 2; ++h) {
      #pragma unroll
      for (int kt = 0; kt < 4; ++kt) {
        u32 d0 = cvtpk(st[h][kt][0], st[h][kt][1]);
        u32 d1 = cvtpk(st[h][kt][2], st[h][kt][3]);
        u32* p = &PLd[wv][l15][kt * 8 + g * 2];
        p[0] = d0; p[1] = d1;
      }
      __builtin_amdgcn_s_setprio(1);
      #pragma unroll
      for (int c2 = 0; c2 < 2; ++c2) {
        bf16x8 pa = *(const bf16x8*)&PLd[wv][l15][c2 * 16 + g * 4];
        #pragma unroll
        for (int dt = 0; dt < 4; ++dt)
          o[h][dt] = __builtin_amdgcn_mfma_f32_16x16x32_bf16(pa, va[c2][dt], o[h][dt], 0, 0, 0);
      }
      __builtin_amdgcn_s_setprio(0);
    }

    if (cn < nch) {
      #pragma unroll
      for (int kt = 0; kt < 4; ++kt) {
        ka[kt][0] = kb[kt][0];
        ka[kt][1] = kb[kt][1];
      }
    }
  }

  #pragma unroll
  for (int h = 0; h < 2; ++h) {
    float ls = lsum[h];
    ls += __shfl_xor(ls, 16);
    ls += __shfl_xor(ls, 32);
    if (lane < 16) OL[wv][h * 16 + l15] = ls;
  }

  #pragma unroll
  for (int ph = 0; ph < 2; ++ph) {
    #pragma unroll
    for (int dt = 0; dt < 4; ++dt)
      #pragma unroll
      for (int r = 0; r < 4; ++r)
        OO[wv][g * 4 + r][dt * 16 + l15] = o[ph][dt][r];
    __syncthreads();
    #pragma unroll
    for (int e = tid; e < 1024; e += 512) {
      int q = e >> 6, d = e & 63;
      float L = 0.f, O = 0.f;
      #pragma unroll
      for (int w = 0; w < 8; ++w) { L += OL[w][ph * 16 + q]; O += OO[w][q][d]; }
      out[((size_t)b * CUT + i0 + ph * 16 + q) * HD + d] = O / L;
    }
    __syncthreads();
  }
}

extern "C" void kernel_launch(void* const* d_in, const int* in_sizes, int n_in,
                              void* d_out, int out_size, void* d_ws, size_t ws_size,
                              hipStream_t stream) {
  const float* x  = (const float*)d_in[0];
  const float* Wq = (const float*)d_in[1];
  const float* bq = (const float*)d_in[2];
  const float* Wk = (const float*)d_in[3];
  const float* bk = (const float*)d_in[4];
  const float* Wv = (const float*)d_in[5];
  const float* bv = (const float*)d_in[6];
  float* out = (float*)d_out;

  u16* Qb  = (u16*)d_ws;                               // [B*CUT*64] (pre-scaled)
  u16* W3F = Qb + (size_t)BB * CUT * HD;               // [384*512]  frag-ordered W
  u16* KF  = W3F + (size_t)384 * 512;                  // [B*64*8*512] frag-ordered K
  u16* VF  = KF + (size_t)BB * 64 * 8 * 512;           // [B*64*8*512] frag-ordered V

  wtrans_k<<<768, 256, 0, stream>>>(Wk, Wv, Wq, W3F);
  proj_k<<<512, 256, 0, stream>>>(x, W3F, bk, bv, bq, KF, VF, Qb);
  attn_k<<<256, 512, 0, stream>>>(Qb, KF, VF, out);
}